// Round 3
// baseline (174.531 us; speedup 1.0000x reference)
//
#include <hip/hip_runtime.h>
#include <math.h>

#define NB 8
#define NP 64
#define NV 8
#define LP 1024
#define ND 256
#define CHUNK 16
#define NCHUNK (LP / CHUNK)   // 64
#define TWO_PI 6.283185307179586

// ---------------------------------------------------------------------------
// k1: stream ts_embeds [B][LP][V][D], compute per-(b,chunk) partial complex sums
//     partial[b][chunk][0/1][d] = Re/Im( lam^{l0} * sum_{j<16} lam^j * ts_mean[b,l0+j,d] )
// thread t: d-group dg = t&63 (4 consecutive d via float4), v-pair vlo = t>>6 (v, v+4)
// ---------------------------------------------------------------------------
__global__ __launch_bounds__(256) void k1_reduce(
    const float* __restrict__ ts,
    const float* __restrict__ bnu, const float* __restrict__ bth,
    float* __restrict__ partial)
{
  const int b = blockIdx.y;
  const int chunk = blockIdx.x;
  const int tid = threadIdx.x;
  const int dg = tid & 63;
  const int vlo = tid >> 6;
  const int d0 = dg << 2;
  const int l0 = chunk * CHUNK;

  float lre[4], lim[4], qre[4], qim[4], are[4], aim[4], p0re[4], p0im[4];
#pragma unroll
  for (int k = 0; k < 4; ++k) {
    const int d = d0 + k;
    float nu = bnu[d], th = bth[d];
    float e = expf(nu);
    float mag = expf(-e);
    float s, c;
    sincosf(th, &s, &c);
    lre[k] = mag * c; lim[k] = mag * s;
    // lam^{l0}: amplitude exp(-e*l0), angle th*l0 reduced mod 2pi in double
    double ang = fmod((double)th * (double)l0, TWO_PI);
    float m0 = expf(-e * (float)l0);
    float s0, c0;
    sincosf((float)ang, &s0, &c0);
    p0re[k] = m0 * c0; p0im[k] = m0 * s0;
    qre[k] = 1.f; qim[k] = 0.f;
    are[k] = 0.f; aim[k] = 0.f;
  }

  const float4* __restrict__ ts4 = (const float4*)ts;
  size_t base = ((((size_t)b * LP + l0) * NV + vlo) * ND + d0) >> 2;  // float4 idx
  const size_t strideL = (size_t)(NV * ND) >> 2;                      // 512 float4 per l

#pragma unroll 4
  for (int j = 0; j < CHUNK; ++j) {
    float4 a = ts4[base];
    float4 c = ts4[base + (4 * ND >> 2)];   // v+4
    base += strideL;
    float s0 = a.x + c.x, s1 = a.y + c.y, s2 = a.z + c.z, s3 = a.w + c.w;
    // acc += q * s (s real); q *= lam
    are[0] = fmaf(qre[0], s0, are[0]); aim[0] = fmaf(qim[0], s0, aim[0]);
    are[1] = fmaf(qre[1], s1, are[1]); aim[1] = fmaf(qim[1], s1, aim[1]);
    are[2] = fmaf(qre[2], s2, are[2]); aim[2] = fmaf(qim[2], s2, aim[2]);
    are[3] = fmaf(qre[3], s3, are[3]); aim[3] = fmaf(qim[3], s3, aim[3]);
#pragma unroll
    for (int k = 0; k < 4; ++k) {
      float nr = qre[k] * lre[k] - qim[k] * lim[k];
      float ni = qre[k] * lim[k] + qim[k] * lre[k];
      qre[k] = nr; qim[k] = ni;
    }
  }

  __shared__ float red[256][8];
#pragma unroll
  for (int k = 0; k < 4; ++k) {
    // partial = lam^{l0} * acc * (1/8)  (1/8 = mean over V)
    red[tid][2 * k]     = (p0re[k] * are[k] - p0im[k] * aim[k]) * 0.125f;
    red[tid][2 * k + 1] = (p0re[k] * aim[k] + p0im[k] * are[k]) * 0.125f;
  }
  __syncthreads();
  if (tid < 64) {
    float rr[4], ri[4];
#pragma unroll
    for (int k = 0; k < 4; ++k) {
      rr[k] = red[tid][2 * k] + red[tid + 64][2 * k] + red[tid + 128][2 * k] + red[tid + 192][2 * k];
      ri[k] = red[tid][2 * k + 1] + red[tid + 64][2 * k + 1] + red[tid + 128][2 * k + 1] + red[tid + 192][2 * k + 1];
    }
    float* pr = partial + (((size_t)b * NCHUNK + chunk) * 2 + 0) * ND;
    float* pi = partial + (((size_t)b * NCHUNK + chunk) * 2 + 1) * ND;
    ((float4*)pr)[tid] = make_float4(rr[0], rr[1], rr[2], rr[3]);
    ((float4*)pi)[tid] = make_float4(ri[0], ri[1], ri[2], ri[3]);
  }
}

// ---------------------------------------------------------------------------
// k2: per (b,d): S' = sum(partials) + signal*(1-lam^LP)/(1-lam); then
//     backward recurrence T[t] = xp[t] + lam_b*T[t+1] (T[64]=S'), y_bwd = Re(g_b*T)
//     forward  recurrence f[t] = lam_f*f[t-1] + xp[t],           y_fwd = Re(g_f*f)
//     Y[b][t][0:256] = y_fwd, Y[b][t][256:512] = y_bwd
// memory is 512 KB total; read twice from global (L2-resident), no LDS.
// ---------------------------------------------------------------------------
__global__ __launch_bounds__(256) void k2_recur(
    const float* __restrict__ partial,
    const float* __restrict__ memory,
    const float* __restrict__ fnu, const float* __restrict__ fth,
    const float* __restrict__ fgr, const float* __restrict__ fgi,
    const float* __restrict__ bnu, const float* __restrict__ bth,
    const float* __restrict__ bgr, const float* __restrict__ bgi,
    const float* __restrict__ prefix, const float* __restrict__ signal,
    float* __restrict__ Y)
{
  const int b = blockIdx.x;
  const int d = threadIdx.x;

  float fe = expf(fnu[d]); float fmag = expf(-fe);
  float fs, fc; sincosf(fth[d], &fs, &fc);
  const float lfre = fmag * fc, lfim = fmag * fs;
  float be = expf(bnu[d]); float bmag = expf(-be);
  float bs, bc; sincosf(bth[d], &bs, &bc);
  const float lbre = bmag * bc, lbim = bmag * bs;
  const float gfr = fgr[d], gfi = fgi[d], gbr = bgr[d], gbi = bgi[d];
  const float pfx = prefix[d], sig = signal[d];

  // reduce chunk partials
  float sre = 0.f, sim = 0.f;
  for (int c = 0; c < NCHUNK; ++c) {
    sre += partial[(((size_t)b * NCHUNK + c) * 2 + 0) * ND + d];
    sim += partial[(((size_t)b * NCHUNK + c) * 2 + 1) * ND + d];
  }
  // signal term: sig * (1 - lam^LP) / (1 - lam)
  {
    double angL = fmod((double)bth[d] * (double)LP, TWO_PI);
    float mL = expf(-be * (float)LP);
    float sL, cL; sincosf((float)angL, &sL, &cL);
    float nre = 1.f - mL * cL, nim = -mL * sL;
    float dre = 1.f - lbre, dim = -lbim;
    float den = dre * dre + dim * dim;
    sre += sig * (nre * dre + nim * dim) / den;
    sim += sig * (nim * dre - nre * dim) / den;
  }

  const float* memb = memory + (size_t)b * NP * ND;

  // backward
  float cre = sre, cim = sim;
  for (int t = NP - 1; t >= 0; --t) {
    float x = memb[(size_t)t * ND + d] + pfx;
    float nr = fmaf(lbre, cre, fmaf(-lbim, cim, x));
    float ni = fmaf(lbre, cim, lbim * cre);
    cre = nr; cim = ni;
    Y[(size_t)(b * NP + t) * (2 * ND) + ND + d] = gbr * cre - gbi * cim;
  }
  // forward
  float fre = 0.f, fim = 0.f;
  for (int t = 0; t < NP; ++t) {
    float x = memb[(size_t)t * ND + d] + pfx;
    float nr = fmaf(lfre, fre, fmaf(-lfim, fim, x));
    float ni = fmaf(lfre, fim, lfim * fre);
    fre = nr; fim = ni;
    Y[(size_t)(b * NP + t) * (2 * ND) + d] = gfr * fre - gfi * fim;
  }
}

// ---------------------------------------------------------------------------
// k3: out[m][j] = sum_k Y[m][k] * W[j][k] + bias[j];  M=512, K=512, N=256
// block: 4 m-rows x all 256 j; W staged transposed in LDS per 32-k chunk
// static LDS: 8 KB (Ys) + 33 KB (Wl) = 41 KB
// ---------------------------------------------------------------------------
#define TM 4
__global__ __launch_bounds__(256) void k3_gemm(
    const float* __restrict__ Y,
    const float* __restrict__ W,
    const float* __restrict__ bias,
    float* __restrict__ out)
{
  const int m0 = blockIdx.x * TM;
  const int j = threadIdx.x;
  __shared__ float Ys[TM][512];
  __shared__ float Wl[32][257];

#pragma unroll
  for (int r = 0; r < TM * 512 / 256; ++r) {   // 8
    int idx = r * 256 + j;
    Ys[idx >> 9][idx & 511] = Y[(size_t)m0 * 512 + idx];
  }
  float acc[TM] = {0.f, 0.f, 0.f, 0.f};

  for (int kc = 0; kc < 16; ++kc) {
    __syncthreads();   // protects Ys (first iter) and Wl reuse
#pragma unroll 4
    for (int r = 0; r < 32; ++r) {
      int idx = r * 256 + j;        // 8192 elements / 256 threads
      int jj = idx >> 5, kk = idx & 31;
      Wl[kk][jj] = W[(size_t)jj * 512 + kc * 32 + kk];
    }
    __syncthreads();
#pragma unroll
    for (int kk = 0; kk < 32; ++kk) {
      float w = Wl[kk][j];
#pragma unroll
      for (int mm = 0; mm < TM; ++mm)
        acc[mm] = fmaf(Ys[mm][kc * 32 + kk], w, acc[mm]);
    }
  }
  float bj = bias[j];
#pragma unroll
  for (int mm = 0; mm < TM; ++mm)
    out[(size_t)(m0 + mm) * 256 + j] = acc[mm] + bj;
}

extern "C" void kernel_launch(void* const* d_in, const int* in_sizes, int n_in,
                              void* d_out, int out_size, void* d_ws, size_t ws_size,
                              hipStream_t stream) {
  const float* memory = (const float*)d_in[0];
  const float* ts     = (const float*)d_in[1];
  const float* fnu    = (const float*)d_in[2];
  const float* fth    = (const float*)d_in[3];
  const float* fgr    = (const float*)d_in[4];
  const float* fgi    = (const float*)d_in[5];
  const float* bnu    = (const float*)d_in[6];
  const float* bth    = (const float*)d_in[7];
  const float* bgr    = (const float*)d_in[8];
  const float* bgi    = (const float*)d_in[9];
  const float* W      = (const float*)d_in[10];
  const float* bias   = (const float*)d_in[11];
  const float* prefix = (const float*)d_in[12];
  const float* signal = (const float*)d_in[13];
  float* out = (float*)d_out;

  // workspace layout: partial (1 MB) | Y (1 MB)
  const size_t n_partial = (size_t)NB * NCHUNK * 2 * ND;   // 262144 floats
  const size_t n_Y       = (size_t)NB * NP * 2 * ND;       // 262144 floats
  const size_t needed    = (n_partial + n_Y) * sizeof(float);
  if (ws_size < needed) {
    // Workspace too small: launching would fault and wedge the container.
    // Skip (output stays zero) so the harness reports a readable absmax
    // failure instead of a container crash.
    return;
  }

  float* partial = (float*)d_ws;
  float* Ybuf    = partial + n_partial;

  k1_reduce<<<dim3(NCHUNK, NB), 256, 0, stream>>>(ts, bnu, bth, partial);
  k2_recur<<<dim3(NB), 256, 0, stream>>>(partial, memory, fnu, fth, fgr, fgi,
                                         bnu, bth, bgr, bgi, prefix, signal, Ybuf);
  k3_gemm<<<dim3(128), 256, 0, stream>>>(Ybuf, W, bias, out);
}

// Round 4
// 139.525 us; speedup vs baseline: 1.2509x; 1.2509x over previous
//
#include <hip/hip_runtime.h>
#include <math.h>

#define NB 8
#define NP 64
#define NV 8
#define LP 1024
#define ND 256
#define CHUNK 16
#define NCHUNK (LP / CHUNK)   // 64
#define KS 8                  // k3 k-slices
#define KSL 64                // k3 k-slice length
#define TWO_PI 6.283185307179586

// ---------------------------------------------------------------------------
// k1: stream ts_embeds [B][LP][V][D], per-(b,chunk) partial complex sums
//     partial[b][chunk][0/1][d] = Re/Im( lam^{l0} * sum_{j<16} lam^j * ts_mean[b,l0+j,d] )
// ---------------------------------------------------------------------------
__global__ __launch_bounds__(256) void k1_reduce(
    const float* __restrict__ ts,
    const float* __restrict__ bnu, const float* __restrict__ bth,
    float* __restrict__ partial)
{
  const int b = blockIdx.y;
  const int chunk = blockIdx.x;
  const int tid = threadIdx.x;
  const int dg = tid & 63;
  const int vlo = tid >> 6;
  const int d0 = dg << 2;
  const int l0 = chunk * CHUNK;

  float lre[4], lim[4], qre[4], qim[4], are[4], aim[4], p0re[4], p0im[4];
#pragma unroll
  for (int k = 0; k < 4; ++k) {
    const int d = d0 + k;
    float nu = bnu[d], th = bth[d];
    float e = expf(nu);
    float mag = expf(-e);
    float s, c;
    sincosf(th, &s, &c);
    lre[k] = mag * c; lim[k] = mag * s;
    double ang = fmod((double)th * (double)l0, TWO_PI);
    float m0 = expf(-e * (float)l0);
    float s0, c0;
    sincosf((float)ang, &s0, &c0);
    p0re[k] = m0 * c0; p0im[k] = m0 * s0;
    qre[k] = 1.f; qim[k] = 0.f;
    are[k] = 0.f; aim[k] = 0.f;
  }

  const float4* __restrict__ ts4 = (const float4*)ts;
  size_t base = ((((size_t)b * LP + l0) * NV + vlo) * ND + d0) >> 2;
  const size_t strideL = (size_t)(NV * ND) >> 2;

#pragma unroll 8
  for (int j = 0; j < CHUNK; ++j) {
    float4 a = ts4[base];
    float4 c = ts4[base + (4 * ND >> 2)];   // v+4
    base += strideL;
    float s0 = a.x + c.x, s1 = a.y + c.y, s2 = a.z + c.z, s3 = a.w + c.w;
    are[0] = fmaf(qre[0], s0, are[0]); aim[0] = fmaf(qim[0], s0, aim[0]);
    are[1] = fmaf(qre[1], s1, are[1]); aim[1] = fmaf(qim[1], s1, aim[1]);
    are[2] = fmaf(qre[2], s2, are[2]); aim[2] = fmaf(qim[2], s2, aim[2]);
    are[3] = fmaf(qre[3], s3, are[3]); aim[3] = fmaf(qim[3], s3, aim[3]);
#pragma unroll
    for (int k = 0; k < 4; ++k) {
      float nr = qre[k] * lre[k] - qim[k] * lim[k];
      float ni = qre[k] * lim[k] + qim[k] * lre[k];
      qre[k] = nr; qim[k] = ni;
    }
  }

  __shared__ float red[256][8];
#pragma unroll
  for (int k = 0; k < 4; ++k) {
    red[tid][2 * k]     = (p0re[k] * are[k] - p0im[k] * aim[k]) * 0.125f;
    red[tid][2 * k + 1] = (p0re[k] * aim[k] + p0im[k] * are[k]) * 0.125f;
  }
  __syncthreads();
  if (tid < 64) {
    float rr[4], ri[4];
#pragma unroll
    for (int k = 0; k < 4; ++k) {
      rr[k] = red[tid][2 * k] + red[tid + 64][2 * k] + red[tid + 128][2 * k] + red[tid + 192][2 * k];
      ri[k] = red[tid][2 * k + 1] + red[tid + 64][2 * k + 1] + red[tid + 128][2 * k + 1] + red[tid + 192][2 * k + 1];
    }
    float* pr = partial + (((size_t)b * NCHUNK + chunk) * 2 + 0) * ND;
    float* pi = partial + (((size_t)b * NCHUNK + chunk) * 2 + 1) * ND;
    ((float4*)pr)[tid] = make_float4(rr[0], rr[1], rr[2], rr[3]);
    ((float4*)pi)[tid] = make_float4(ri[0], ri[1], ri[2], ri[3]);
  }
}

// ---------------------------------------------------------------------------
// k2: grid (NB, 2). y=0: forward recurrence; y=1: partial-reduce + signal
//     closed form + backward recurrence. memory rows preloaded to registers
//     (fully unrolled static indexing -> VGPRs, no scratch).
// ---------------------------------------------------------------------------
__global__ __launch_bounds__(256) void k2_recur(
    const float* __restrict__ partial,
    const float* __restrict__ memory,
    const float* __restrict__ fnu, const float* __restrict__ fth,
    const float* __restrict__ fgr, const float* __restrict__ fgi,
    const float* __restrict__ bnu, const float* __restrict__ bth,
    const float* __restrict__ bgr, const float* __restrict__ bgi,
    const float* __restrict__ prefix, const float* __restrict__ signal,
    float* __restrict__ Y)
{
  const int b = blockIdx.x;
  const int d = threadIdx.x;
  const float pfx = prefix[d];
  const float* memb = memory + (size_t)b * NP * ND;

  float xv[NP];
#pragma unroll
  for (int t = 0; t < NP; ++t) xv[t] = memb[(size_t)t * ND + d] + pfx;

  if (blockIdx.y == 0) {
    // forward
    float fe = expf(fnu[d]); float fmag = expf(-fe);
    float fs, fc; sincosf(fth[d], &fs, &fc);
    const float lre = fmag * fc, lim_ = fmag * fs;
    const float gr = fgr[d], gi = fgi[d];
    float cre = 0.f, cim = 0.f;
#pragma unroll
    for (int t = 0; t < NP; ++t) {
      float nr = fmaf(lre, cre, fmaf(-lim_, cim, xv[t]));
      float ni = fmaf(lre, cim, lim_ * cre);
      cre = nr; cim = ni;
      Y[(size_t)(b * NP + t) * (2 * ND) + d] = gr * cre - gi * cim;
    }
  } else {
    // backward
    float be = expf(bnu[d]); float bmag = expf(-be);
    float bs, bc; sincosf(bth[d], &bs, &bc);
    const float lre = bmag * bc, lim_ = bmag * bs;
    const float gr = bgr[d], gi = bgi[d];
    const float sig = signal[d];

    float sre = 0.f, sim = 0.f;
#pragma unroll 4
    for (int c = 0; c < NCHUNK; ++c) {
      sre += partial[(((size_t)b * NCHUNK + c) * 2 + 0) * ND + d];
      sim += partial[(((size_t)b * NCHUNK + c) * 2 + 1) * ND + d];
    }
    {
      double angL = fmod((double)bth[d] * (double)LP, TWO_PI);
      float mL = expf(-be * (float)LP);
      float sL, cL; sincosf((float)angL, &sL, &cL);
      float nre = 1.f - mL * cL, nim = -mL * sL;
      float dre = 1.f - lre, dim_ = -lim_;
      float den = dre * dre + dim_ * dim_;
      sre += sig * (nre * dre + nim * dim_) / den;
      sim += sig * (nim * dre - nre * dim_) / den;
    }
    float cre = sre, cim = sim;
#pragma unroll
    for (int t = NP - 1; t >= 0; --t) {
      float nr = fmaf(lre, cre, fmaf(-lim_, cim, xv[t]));
      float ni = fmaf(lre, cim, lim_ * cre);
      cre = nr; cim = ni;
      Y[(size_t)(b * NP + t) * (2 * ND) + ND + d] = gr * cre - gi * cim;
    }
  }
}

// ---------------------------------------------------------------------------
// k3_part: k-split partial GEMM. grid (16 m-tiles, 2 j-tiles, KS slices).
// Block: m-tile 32, j-tile 128, k-slice 64. W in registers (float4 x16),
// Y-tile in LDS (broadcast reads). gpart[slice][m][j] partial sums.
// ---------------------------------------------------------------------------
__global__ __launch_bounds__(256) void k3_part(
    const float* __restrict__ Y,
    const float* __restrict__ W,
    float* __restrict__ gpart)
{
  const int m0 = blockIdx.x * 32;
  const int j0 = blockIdx.y * 128;
  const int s0 = blockIdx.z * KSL;
  const int t = threadIdx.x;
  const int j = t & 127;
  const int mh = t >> 7;   // 0/1

  __shared__ float Ys[32][KSL + 4];

  const float4* __restrict__ Y4 = (const float4*)Y;
  const float4* __restrict__ W4 = (const float4*)W;

#pragma unroll
  for (int r = 0; r < 2; ++r) {
    int q = r * 256 + t;              // 0..511
    int m = q >> 4, kq = q & 15;
    float4 v = Y4[(size_t)(m0 + m) * 128 + (s0 >> 2) + kq];
    *(float4*)&Ys[m][kq * 4] = v;
  }

  float4 wq[16];
#pragma unroll
  for (int kq = 0; kq < 16; ++kq)
    wq[kq] = W4[(size_t)(j0 + j) * 128 + (s0 >> 2) + kq];

  __syncthreads();

  float acc[16];
#pragma unroll
  for (int m = 0; m < 16; ++m) acc[m] = 0.f;

#pragma unroll
  for (int kq = 0; kq < 16; ++kq) {
    float4 w = wq[kq];
#pragma unroll
    for (int m = 0; m < 16; ++m) {
      float4 y = *(const float4*)&Ys[mh * 16 + m][kq * 4];
      acc[m] = fmaf(y.x, w.x, acc[m]);
      acc[m] = fmaf(y.y, w.y, acc[m]);
      acc[m] = fmaf(y.z, w.z, acc[m]);
      acc[m] = fmaf(y.w, w.w, acc[m]);
    }
  }

  float* gp = gpart + (size_t)blockIdx.z * (512 * 256);
#pragma unroll
  for (int m = 0; m < 16; ++m)
    gp[(size_t)(m0 + mh * 16 + m) * 256 + j0 + j] = acc[m];
}

// ---------------------------------------------------------------------------
// k3_reduce: out = sum_slices gpart + bias. float4-wide, 128 blocks.
// ---------------------------------------------------------------------------
__global__ __launch_bounds__(256) void k3_reduce(
    const float* __restrict__ gpart,
    const float* __restrict__ bias,
    float* __restrict__ out)
{
  const int idx = blockIdx.x * 256 + threadIdx.x;   // float4 index, 32768 total
  const float4* __restrict__ g4 = (const float4*)gpart;
  float4 s = g4[idx];
#pragma unroll
  for (int sl = 1; sl < KS; ++sl) {
    float4 v = g4[(size_t)sl * 32768 + idx];
    s.x += v.x; s.y += v.y; s.z += v.z; s.w += v.w;
  }
  float4 bb = ((const float4*)bias)[idx & 63];
  s.x += bb.x; s.y += bb.y; s.z += bb.z; s.w += bb.w;
  ((float4*)out)[idx] = s;
}

// ---------------------------------------------------------------------------
// k3_gemm: fallback direct GEMM (known-correct, used only if ws is small)
// ---------------------------------------------------------------------------
#define TM 4
__global__ __launch_bounds__(256) void k3_gemm(
    const float* __restrict__ Y,
    const float* __restrict__ W,
    const float* __restrict__ bias,
    float* __restrict__ out)
{
  const int m0 = blockIdx.x * TM;
  const int j = threadIdx.x;
  __shared__ float Ys[TM][512];
  __shared__ float Wl[32][257];

#pragma unroll
  for (int r = 0; r < TM * 512 / 256; ++r) {
    int idx = r * 256 + j;
    Ys[idx >> 9][idx & 511] = Y[(size_t)m0 * 512 + idx];
  }
  float acc[TM] = {0.f, 0.f, 0.f, 0.f};

  for (int kc = 0; kc < 16; ++kc) {
    __syncthreads();
#pragma unroll 4
    for (int r = 0; r < 32; ++r) {
      int idx = r * 256 + j;
      int jj = idx >> 5, kk = idx & 31;
      Wl[kk][jj] = W[(size_t)jj * 512 + kc * 32 + kk];
    }
    __syncthreads();
#pragma unroll
    for (int kk = 0; kk < 32; ++kk) {
      float w = Wl[kk][j];
#pragma unroll
      for (int mm = 0; mm < TM; ++mm)
        acc[mm] = fmaf(Ys[mm][kc * 32 + kk], w, acc[mm]);
    }
  }
  float bj = bias[j];
#pragma unroll
  for (int mm = 0; mm < TM; ++mm)
    out[(size_t)(m0 + mm) * 256 + j] = acc[mm] + bj;
}

extern "C" void kernel_launch(void* const* d_in, const int* in_sizes, int n_in,
                              void* d_out, int out_size, void* d_ws, size_t ws_size,
                              hipStream_t stream) {
  const float* memory = (const float*)d_in[0];
  const float* ts     = (const float*)d_in[1];
  const float* fnu    = (const float*)d_in[2];
  const float* fth    = (const float*)d_in[3];
  const float* fgr    = (const float*)d_in[4];
  const float* fgi    = (const float*)d_in[5];
  const float* bnu    = (const float*)d_in[6];
  const float* bth    = (const float*)d_in[7];
  const float* bgr    = (const float*)d_in[8];
  const float* bgi    = (const float*)d_in[9];
  const float* W      = (const float*)d_in[10];
  const float* bias   = (const float*)d_in[11];
  const float* prefix = (const float*)d_in[12];
  const float* signal = (const float*)d_in[13];
  float* out = (float*)d_out;

  const size_t n_partial = (size_t)NB * NCHUNK * 2 * ND;   // 262144 floats (1 MB)
  const size_t n_Y       = (size_t)NB * NP * 2 * ND;       // 262144 floats (1 MB)
  const size_t n_gpart   = (size_t)KS * 512 * 256;         // 1048576 floats (4 MB)
  const size_t need_min  = (n_partial + n_Y) * sizeof(float);
  const size_t need_full = (n_partial + n_Y + n_gpart) * sizeof(float);
  if (ws_size < need_min) return;   // readable failure instead of OOB fault

  float* partial = (float*)d_ws;
  float* Ybuf    = partial + n_partial;

  k1_reduce<<<dim3(NCHUNK, NB), 256, 0, stream>>>(ts, bnu, bth, partial);
  k2_recur<<<dim3(NB, 2), 256, 0, stream>>>(partial, memory, fnu, fth, fgr, fgi,
                                            bnu, bth, bgr, bgi, prefix, signal, Ybuf);
  if (ws_size >= need_full) {
    float* gpart = Ybuf + n_Y;
    k3_part<<<dim3(16, 2, KS), 256, 0, stream>>>(Ybuf, W, gpart);
    k3_reduce<<<dim3(128), 256, 0, stream>>>(gpart, bias, out);
  } else {
    k3_gemm<<<dim3(128), 256, 0, stream>>>(Ybuf, W, bias, out);
  }
}